// Round 1
// baseline (238.047 us; speedup 1.0000x reference)
//
#include <hip/hip_runtime.h>

#define BATCH 16384
#define D 128
#define H1C 256
#define H2C 128

__device__ __forceinline__ float relu_f(float x) { return fmaxf(x, 0.0f); }

// -------------------------------------------------------------------------
// Kernel 1: cross-compress (2 layers) per row + rec_target passthrough.
// One wave (64 lanes) per batch row; each lane owns 2 of the 128 elements.
// -------------------------------------------------------------------------
__global__ __launch_bounds__(256) void cross_kernel(
    const int* __restrict__ item_ids, const float* __restrict__ rec_target,
    const float* __restrict__ item_tbl, const float* __restrict__ entity_tbl,
    const float* __restrict__ w_vv, const float* __restrict__ w_ev,
    const float* __restrict__ w_ve, const float* __restrict__ w_ee,
    const float* __restrict__ bias_v, const float* __restrict__ bias_e,
    float* __restrict__ high, float* __restrict__ out)
{
    const int gid  = blockIdx.x * 256 + threadIdx.x;
    const int row  = gid >> 6;
    const int lane = threadIdx.x & 63;
    if (row >= BATCH) return;

    const int id = item_ids[row];
    const float* ir = item_tbl   + (long)id * D;
    const float* hr = entity_tbl + (long)id * D;
    float it0 = ir[lane], it1 = ir[lane + 64];
    float hd0 = hr[lane], hd1 = hr[lane + 64];
    const float wvv0 = w_vv[lane], wvv1 = w_vv[lane + 64];
    const float wev0 = w_ev[lane], wev1 = w_ev[lane + 64];
    const float wve0 = w_ve[lane], wve1 = w_ve[lane + 64];
    const float wee0 = w_ee[lane], wee1 = w_ee[lane + 64];
    const float bv = bias_v[0], be = bias_e[0];

    #pragma unroll
    for (int l = 0; l < 2; ++l) {
        float hv = hd0 * wvv0 + hd1 * wvv1;   // head @ w_vv
        float iv = it0 * wev0 + it1 * wev1;   // item @ w_ev
        float he = hd0 * wve0 + hd1 * wve1;   // head @ w_ve
        float ie = it0 * wee0 + it1 * wee1;   // item @ w_ee
        #pragma unroll
        for (int off = 32; off > 0; off >>= 1) {
            hv += __shfl_xor(hv, off, 64);
            iv += __shfl_xor(iv, off, 64);
            he += __shfl_xor(he, off, 64);
            ie += __shfl_xor(ie, off, 64);
        }
        float ni0 = it0 * hv + hd0 * iv + bv;
        float ni1 = it1 * hv + hd1 * iv + bv;
        float nh0 = it0 * he + hd0 * ie + be;
        float nh1 = it1 * he + hd1 * ie + be;
        it0 = ni0; it1 = ni1; hd0 = nh0; hd1 = nh1;
    }
    // item embedding -> high[:, 128:256]
    high[(long)row * 256 + 128 + lane]      = it0;
    high[(long)row * 256 + 128 + 64 + lane] = it1;
    if (lane == 0) out[BATCH + row] = rec_target[row];
}

// -------------------------------------------------------------------------
// 4x4 register-tile GEMM micro-kernel: acc[j][i] += A[rb+j][k] * W[k][cb+i]
// A in LDS (wave-broadcast b128 reads along K), W from global (float4, L1/L2).
// -------------------------------------------------------------------------
__device__ __forceinline__ void gemm_tile_4x4(
    const float* __restrict__ As, int lda, int rbase,
    const float* __restrict__ W, int ldw, int cbase, int K,
    float acc[4][4])
{
    for (int k = 0; k < K; k += 4) {
        float4 a4[4];
        #pragma unroll
        for (int j = 0; j < 4; ++j)
            a4[j] = *(const float4*)&As[(rbase + j) * lda + k];
        float4 w4[4];
        #pragma unroll
        for (int kk = 0; kk < 4; ++kk)
            w4[kk] = *(const float4*)&W[(long)(k + kk) * ldw + cbase];
        #pragma unroll
        for (int j = 0; j < 4; ++j) {
            const float aj[4] = {a4[j].x, a4[j].y, a4[j].z, a4[j].w};
            #pragma unroll
            for (int kk = 0; kk < 4; ++kk) {
                const float* w = (const float*)&w4[kk];
                acc[j][0] += aj[kk] * w[0];
                acc[j][1] += aj[kk] * w[1];
                acc[j][2] += aj[kk] * w[2];
                acc[j][3] += aj[kk] * w[3];
            }
        }
    }
}

// -------------------------------------------------------------------------
// Kernel 2: user MLP, both layers fused.  32 rows/block, 256 threads,
// each thread computes a 4-row x 4-col tile.  Writes high[:, 0:128].
// -------------------------------------------------------------------------
__global__ __launch_bounds__(256) void user_kernel(
    const int* __restrict__ user_ids, const float* __restrict__ user_tbl,
    const float* __restrict__ Wu, const float* __restrict__ bu,
    float* __restrict__ high)
{
    __shared__ float s0[32][128];
    __shared__ float s1[32][128];
    const int row0 = blockIdx.x * 32;
    const int tid  = threadIdx.x;

    // gather 32 user rows (float4-coalesced within each row)
    for (int e = tid; e < 32 * 32; e += 256) {
        int r = e >> 5, c4 = e & 31;
        float4 v = ((const float4*)(user_tbl + (long)user_ids[row0 + r] * D))[c4];
        ((float4*)&s0[r][0])[c4] = v;
    }
    __syncthreads();

    const int cg = tid & 31;   // cols cg*4 .. cg*4+3
    const int rg = tid >> 5;   // rows rg*4 .. rg*4+3
    const int col = cg * 4;
    const float4 bias = *(const float4*)&bu[col];

    float acc[4][4];
    // layer 1
    #pragma unroll
    for (int j = 0; j < 4; ++j) {
        acc[j][0] = bias.x; acc[j][1] = bias.y; acc[j][2] = bias.z; acc[j][3] = bias.w;
    }
    gemm_tile_4x4(&s0[0][0], 128, rg * 4, Wu, 128, col, 128, acc);
    #pragma unroll
    for (int j = 0; j < 4; ++j) {
        float4 v = make_float4(relu_f(acc[j][0]), relu_f(acc[j][1]),
                               relu_f(acc[j][2]), relu_f(acc[j][3]));
        *(float4*)&s1[rg * 4 + j][col] = v;
    }
    __syncthreads();

    // layer 2
    #pragma unroll
    for (int j = 0; j < 4; ++j) {
        acc[j][0] = bias.x; acc[j][1] = bias.y; acc[j][2] = bias.z; acc[j][3] = bias.w;
    }
    gemm_tile_4x4(&s1[0][0], 128, rg * 4, Wu, 128, col, 128, acc);
    #pragma unroll
    for (int j = 0; j < 4; ++j) {
        float4 v = make_float4(relu_f(acc[j][0]), relu_f(acc[j][1]),
                               relu_f(acc[j][2]), relu_f(acc[j][3]));
        *(float4*)&high[(long)(row0 + rg * 4 + j) * 256 + col] = v;
    }
}

// -------------------------------------------------------------------------
// Kernel 3: h1 = relu(high @ W1 + b1).  M-tile 32, N-tile 128 (grid.y = 2).
// -------------------------------------------------------------------------
__global__ __launch_bounds__(256) void mlp1_kernel(
    const float* __restrict__ high, const float* __restrict__ W1,
    const float* __restrict__ b1, float* __restrict__ h1out)
{
    __shared__ float hs[32][256];
    const int row0 = blockIdx.x * 32;
    const int col0 = blockIdx.y * 128;
    const int tid  = threadIdx.x;

    for (int e = tid; e < 32 * 64; e += 256) {
        int r = e >> 6, c4 = e & 63;
        ((float4*)&hs[r][0])[c4] = ((const float4*)(high + (long)(row0 + r) * 256))[c4];
    }
    __syncthreads();

    const int cg = tid & 31, rg = tid >> 5;
    const int col = col0 + cg * 4;
    const float4 bias = *(const float4*)&b1[col];
    float acc[4][4];
    #pragma unroll
    for (int j = 0; j < 4; ++j) {
        acc[j][0] = bias.x; acc[j][1] = bias.y; acc[j][2] = bias.z; acc[j][3] = bias.w;
    }
    gemm_tile_4x4(&hs[0][0], 256, rg * 4, W1, 256, col, 256, acc);
    #pragma unroll
    for (int j = 0; j < 4; ++j) {
        float4 v = make_float4(relu_f(acc[j][0]), relu_f(acc[j][1]),
                               relu_f(acc[j][2]), relu_f(acc[j][3]));
        *(float4*)&h1out[(long)(row0 + rg * 4 + j) * 256 + col] = v;
    }
}

// -------------------------------------------------------------------------
// Kernel 4: h2 = relu(h1 @ W2 + b2); out = relu(h2 @ W3 + b3) fused.
// -------------------------------------------------------------------------
__global__ __launch_bounds__(256) void mlp2_kernel(
    const float* __restrict__ h1in, const float* __restrict__ W2,
    const float* __restrict__ b2, const float* __restrict__ W3,
    const float* __restrict__ b3, float* __restrict__ out)
{
    __shared__ float hs[32][256];
    __shared__ float h2s[32][128];
    const int row0 = blockIdx.x * 32;
    const int tid  = threadIdx.x;

    for (int e = tid; e < 32 * 64; e += 256) {
        int r = e >> 6, c4 = e & 63;
        ((float4*)&hs[r][0])[c4] = ((const float4*)(h1in + (long)(row0 + r) * 256))[c4];
    }
    __syncthreads();

    const int cg = tid & 31, rg = tid >> 5;
    const int col = cg * 4;
    const float4 bias = *(const float4*)&b2[col];
    float acc[4][4];
    #pragma unroll
    for (int j = 0; j < 4; ++j) {
        acc[j][0] = bias.x; acc[j][1] = bias.y; acc[j][2] = bias.z; acc[j][3] = bias.w;
    }
    gemm_tile_4x4(&hs[0][0], 256, rg * 4, W2, 128, col, 256, acc);
    #pragma unroll
    for (int j = 0; j < 4; ++j) {
        float4 v = make_float4(relu_f(acc[j][0]), relu_f(acc[j][1]),
                               relu_f(acc[j][2]), relu_f(acc[j][3]));
        *(float4*)&h2s[rg * 4 + j][col] = v;
    }
    __syncthreads();

    // layer 3: per-row dot with W3 (128), 8 threads per row
    const int g = tid >> 3;        // row within tile (0..31)
    const int l = tid & 7;
    float p = 0.0f;
    #pragma unroll
    for (int k = l; k < 128; k += 8) p += h2s[g][k] * W3[k];
    p += __shfl_xor(p, 4, 64);
    p += __shfl_xor(p, 2, 64);
    p += __shfl_xor(p, 1, 64);
    if (l == 0) out[row0 + g] = relu_f(p + b3[0]);
}

// -------------------------------------------------------------------------
extern "C" void kernel_launch(void* const* d_in, const int* in_sizes, int n_in,
                              void* d_out, int out_size, void* d_ws, size_t ws_size,
                              hipStream_t stream)
{
    const int*   user_ids   = (const int*)  d_in[0];
    const int*   item_ids   = (const int*)  d_in[1];
    const float* rec_target = (const float*)d_in[2];
    const float* user_tbl   = (const float*)d_in[3];
    const float* item_tbl   = (const float*)d_in[4];
    const float* entity_tbl = (const float*)d_in[5];
    const float* w_vv       = (const float*)d_in[6];
    const float* w_ev       = (const float*)d_in[7];
    const float* w_ve       = (const float*)d_in[8];
    const float* w_ee       = (const float*)d_in[9];
    const float* bias_v     = (const float*)d_in[10];
    const float* bias_e     = (const float*)d_in[11];
    const float* Wu         = (const float*)d_in[12];
    const float* bu         = (const float*)d_in[13];
    const float* W1         = (const float*)d_in[14];
    const float* b1         = (const float*)d_in[15];
    const float* W2         = (const float*)d_in[16];
    const float* b2         = (const float*)d_in[17];
    const float* W3         = (const float*)d_in[18];
    const float* b3         = (const float*)d_in[19];
    float* out = (float*)d_out;

    float* high = (float*)d_ws;                      // [B,256]
    float* h1   = high + (size_t)BATCH * 256;        // [B,256]

    cross_kernel<<<BATCH / 4, 256, 0, stream>>>(
        item_ids, rec_target, item_tbl, entity_tbl,
        w_vv, w_ev, w_ve, w_ee, bias_v, bias_e, high, out);
    user_kernel<<<BATCH / 32, 256, 0, stream>>>(
        user_ids, user_tbl, Wu, bu, high);
    mlp1_kernel<<<dim3(BATCH / 32, 2), 256, 0, stream>>>(
        high, W1, b1, h1);
    mlp2_kernel<<<BATCH / 32, 256, 0, stream>>>(
        h1, W2, b2, W3, b3, out);
}

// Round 2
// 168.078 us; speedup vs baseline: 1.4163x; 1.4163x over previous
//
#include <hip/hip_runtime.h>

#define BATCH 16384
#define DIM 128
#define STRIDE 264   // LDS row stride in bf16 elems (256 + 8 pad -> 2-way banks max)

typedef __attribute__((ext_vector_type(8))) short short8;
typedef __attribute__((ext_vector_type(4))) float floatx4;

__device__ __forceinline__ ushort f2bf(float f) {
    union { float f; uint u; } c; c.f = f;
    return (ushort)((c.u + 0x7FFFu + ((c.u >> 16) & 1u)) >> 16);
}
__device__ __forceinline__ float bf2f(ushort h) {
    union { uint u; float f; } c; c.u = ((uint)h) << 16;
    return c.f;
}
__device__ __forceinline__ ushort4 f4_to_bf4(float4 v) {
    return make_ushort4(f2bf(v.x), f2bf(v.y), f2bf(v.z), f2bf(v.w));
}

// ---------------------------------------------------------------------------
// Weight convert: fp32 [K][N] -> bf16 transposed [N][K], via LDS 64x64 tiles.
// 28 blocks total (Wu: 4, W1: 16, W2: 8).
// ---------------------------------------------------------------------------
__global__ __launch_bounds__(256) void convert_kernel(
    const float* __restrict__ Wu, const float* __restrict__ W1,
    const float* __restrict__ W2, ushort* __restrict__ Wut,
    ushort* __restrict__ W1t, ushort* __restrict__ W2t)
{
    __shared__ float s[64][65];
    const int b = blockIdx.x;
    const float* W; ushort* Wt; int K, N, tk, tn;
    if (b < 4)       { W = Wu; Wt = Wut; K = 128; N = 128; tk = b >> 1;        tn = b & 1; }
    else if (b < 20) { W = W1; Wt = W1t; K = 256; N = 256; tk = (b - 4) >> 2;  tn = (b - 4) & 3; }
    else             { W = W2; Wt = W2t; K = 256; N = 128; tk = (b - 20) >> 1; tn = (b - 20) & 1; }
    const int k0 = tk * 64, n0 = tn * 64;
    const int tx = threadIdx.x & 63, ty = threadIdx.x >> 6;
    #pragma unroll
    for (int i = 0; i < 16; ++i) {
        int r = i * 4 + ty;
        s[r][tx] = W[(size_t)(k0 + r) * N + n0 + tx];
    }
    __syncthreads();
    const int p = threadIdx.x & 31, nb = threadIdx.x >> 5;
    #pragma unroll
    for (int i = 0; i < 8; ++i) {
        int n = i * 8 + nb;
        uint v = (uint)f2bf(s[2 * p][n]) | ((uint)f2bf(s[2 * p + 1][n]) << 16);
        ((uint*)Wt)[(((size_t)(n0 + n) * K + k0) >> 1) + p] = v;
    }
}

// ---------------------------------------------------------------------------
// One MFMA layer: dst[32][N] = relu(src[32][K] @ W + bias), bf16 in/out (LDS),
// weights bf16 transposed [N][K] from global (L2-resident).
// 4 waves; wave handles col tiles nt = wave, wave+4, ...
// ---------------------------------------------------------------------------
template<int K, int N>
__device__ __forceinline__ void layer_mfma(
    const ushort* __restrict__ src, const ushort* __restrict__ Wt,
    const float* __restrict__ bias, ushort* __restrict__ dst, int tid)
{
    const int wave = tid >> 6, lane = tid & 63;
    const int n15 = lane & 15, quad = lane >> 4;
    constexpr int NT = N / 16, KF = K / 32;
    for (int nt = wave; nt < NT; nt += 4) {
        const int n0 = nt * 16;
        short8 bfr[KF];
        const ushort* wrow = Wt + (size_t)(n0 + n15) * K + quad * 8;
        #pragma unroll
        for (int kf = 0; kf < KF; ++kf)
            bfr[kf] = *(const short8*)(wrow + kf * 32);
        const float b = bias[n0 + n15];
        #pragma unroll
        for (int mt = 0; mt < 2; ++mt) {
            floatx4 acc = {0.f, 0.f, 0.f, 0.f};
            const ushort* arow = src + (mt * 16 + n15) * STRIDE + quad * 8;
            #pragma unroll
            for (int kf = 0; kf < KF; ++kf) {
                short8 afr = *(const short8*)(arow + kf * 32);
                acc = __builtin_amdgcn_mfma_f32_16x16x32_bf16(afr, bfr[kf], acc, 0, 0, 0);
            }
            ushort* drow = dst + (mt * 16 + quad * 4) * STRIDE + n0 + n15;
            #pragma unroll
            for (int r = 0; r < 4; ++r)
                drow[r * STRIDE] = f2bf(fmaxf(acc[r] + b, 0.f));
        }
    }
}

// ---------------------------------------------------------------------------
// Fully fused model: 32 rows/block, 512 blocks.
// ---------------------------------------------------------------------------
__global__ __launch_bounds__(256) void fused_kernel(
    const int* __restrict__ user_ids, const int* __restrict__ item_ids,
    const float* __restrict__ rec_target,
    const float* __restrict__ user_tbl, const float* __restrict__ item_tbl,
    const float* __restrict__ entity_tbl,
    const float* __restrict__ w_vv, const float* __restrict__ w_ev,
    const float* __restrict__ w_ve, const float* __restrict__ w_ee,
    const float* __restrict__ bias_v, const float* __restrict__ bias_e,
    const ushort* __restrict__ Wut, const float* __restrict__ bu,
    const ushort* __restrict__ W1t, const float* __restrict__ b1,
    const ushort* __restrict__ W2t, const float* __restrict__ b2,
    const float* __restrict__ W3, const float* __restrict__ b3,
    float* __restrict__ out)
{
    __shared__ ushort bufA[32 * STRIDE];
    __shared__ ushort bufB[32 * STRIDE];
    const int r0  = blockIdx.x * 32;
    const int tid = threadIdx.x;
    const int row = tid >> 3, l = tid & 7;   // 8 threads per row, 16 elems each

    // rec_target passthrough (exact fp32 -> tight 2e-2 threshold on output 1)
    if (tid < 32) out[BATCH + r0 + tid] = rec_target[r0 + tid];

    // --- gather user rows -> bf16 -> bufA cols 0..127 ---
    {
        const int uid = user_ids[r0 + row];
        const float4* src = (const float4*)(user_tbl + (size_t)uid * DIM + l * 16);
        ushort* dst = &bufA[row * STRIDE + l * 16];
        #pragma unroll
        for (int i = 0; i < 4; ++i)
            *(ushort4*)&dst[i * 4] = f4_to_bf4(src[i]);
    }

    // --- cross-compress (2 layers, fp32) -> bf16 -> bufA cols 128..255 ---
    {
        const int id = item_ids[r0 + row];
        const float4* ip = (const float4*)(item_tbl   + (size_t)id * DIM + l * 16);
        const float4* hp = (const float4*)(entity_tbl + (size_t)id * DIM + l * 16);
        float4 it4[4], hd4[4];
        #pragma unroll
        for (int i = 0; i < 4; ++i) { it4[i] = ip[i]; hd4[i] = hp[i]; }
        const float bv = bias_v[0], be = bias_e[0];
        #pragma unroll
        for (int lay = 0; lay < 2; ++lay) {
            float hv = 0.f, iv = 0.f, he = 0.f, ie = 0.f;
            #pragma unroll
            for (int i = 0; i < 4; ++i) {
                float4 wvv = ((const float4*)w_vv)[l * 4 + i];
                float4 wev = ((const float4*)w_ev)[l * 4 + i];
                float4 wve = ((const float4*)w_ve)[l * 4 + i];
                float4 wee = ((const float4*)w_ee)[l * 4 + i];
                hv += hd4[i].x * wvv.x + hd4[i].y * wvv.y + hd4[i].z * wvv.z + hd4[i].w * wvv.w;
                iv += it4[i].x * wev.x + it4[i].y * wev.y + it4[i].z * wev.z + it4[i].w * wev.w;
                he += hd4[i].x * wve.x + hd4[i].y * wve.y + hd4[i].z * wve.z + hd4[i].w * wve.w;
                ie += it4[i].x * wee.x + it4[i].y * wee.y + it4[i].z * wee.z + it4[i].w * wee.w;
            }
            hv += __shfl_xor(hv, 1); hv += __shfl_xor(hv, 2); hv += __shfl_xor(hv, 4);
            iv += __shfl_xor(iv, 1); iv += __shfl_xor(iv, 2); iv += __shfl_xor(iv, 4);
            he += __shfl_xor(he, 1); he += __shfl_xor(he, 2); he += __shfl_xor(he, 4);
            ie += __shfl_xor(ie, 1); ie += __shfl_xor(ie, 2); ie += __shfl_xor(ie, 4);
            #pragma unroll
            for (int i = 0; i < 4; ++i) {
                float4 t = it4[i], h = hd4[i];
                it4[i].x = t.x * hv + h.x * iv + bv;  hd4[i].x = t.x * he + h.x * ie + be;
                it4[i].y = t.y * hv + h.y * iv + bv;  hd4[i].y = t.y * he + h.y * ie + be;
                it4[i].z = t.z * hv + h.z * iv + bv;  hd4[i].z = t.z * he + h.z * ie + be;
                it4[i].w = t.w * hv + h.w * iv + bv;  hd4[i].w = t.w * he + h.w * ie + be;
            }
        }
        ushort* dst = &bufA[row * STRIDE + 128 + l * 16];
        #pragma unroll
        for (int i = 0; i < 4; ++i)
            *(ushort4*)&dst[i * 4] = f4_to_bf4(it4[i]);
    }
    __syncthreads();

    // --- user MLP layer 1: bufA[:,0:128] -> bufB[:,0:128] ---
    layer_mfma<128, 128>(bufA, Wut, bu, bufB, tid);
    __syncthreads();
    // --- user MLP layer 2: bufB -> bufA[:,0:128]  (cols 128..255 = item_c kept) ---
    layer_mfma<128, 128>(bufB, Wut, bu, bufA, tid);
    __syncthreads();
    // --- mlp1: high = bufA[:,0:256] -> bufB[:,0:256] ---
    layer_mfma<256, 256>(bufA, W1t, b1, bufB, tid);
    __syncthreads();
    // --- mlp2: bufB[:,0:256] -> bufA[:,0:128] ---
    layer_mfma<256, 128>(bufB, W2t, b2, bufA, tid);
    __syncthreads();

    // --- mlp3: per-row dot with W3[128] + b3, relu ---
    {
        const ushort* h2 = &bufA[row * STRIDE + l * 16];
        float p = 0.f;
        #pragma unroll
        for (int i = 0; i < 4; ++i) {
            ushort4 h4 = *(const ushort4*)&h2[i * 4];
            float4 w = ((const float4*)W3)[l * 4 + i];
            p += bf2f(h4.x) * w.x + bf2f(h4.y) * w.y + bf2f(h4.z) * w.z + bf2f(h4.w) * w.w;
        }
        p += __shfl_xor(p, 1); p += __shfl_xor(p, 2); p += __shfl_xor(p, 4);
        if (l == 0) out[r0 + row] = fmaxf(p + b3[0], 0.f);
    }
}

// ---------------------------------------------------------------------------
extern "C" void kernel_launch(void* const* d_in, const int* in_sizes, int n_in,
                              void* d_out, int out_size, void* d_ws, size_t ws_size,
                              hipStream_t stream)
{
    const int*   user_ids   = (const int*)  d_in[0];
    const int*   item_ids   = (const int*)  d_in[1];
    const float* rec_target = (const float*)d_in[2];
    const float* user_tbl   = (const float*)d_in[3];
    const float* item_tbl   = (const float*)d_in[4];
    const float* entity_tbl = (const float*)d_in[5];
    const float* w_vv       = (const float*)d_in[6];
    const float* w_ev       = (const float*)d_in[7];
    const float* w_ve       = (const float*)d_in[8];
    const float* w_ee       = (const float*)d_in[9];
    const float* bias_v     = (const float*)d_in[10];
    const float* bias_e     = (const float*)d_in[11];
    const float* Wu         = (const float*)d_in[12];
    const float* bu         = (const float*)d_in[13];
    const float* W1         = (const float*)d_in[14];
    const float* b1         = (const float*)d_in[15];
    const float* W2         = (const float*)d_in[16];
    const float* b2         = (const float*)d_in[17];
    const float* W3         = (const float*)d_in[18];
    const float* b3         = (const float*)d_in[19];
    float* out = (float*)d_out;

    ushort* Wut = (ushort*)d_ws;            // [128][128] bf16, transposed [N][K]
    ushort* W1t = Wut + 128 * 128;          // [256][256]
    ushort* W2t = W1t + 256 * 256;          // [128][256]

    convert_kernel<<<28, 256, 0, stream>>>(Wu, W1, W2, Wut, W1t, W2t);
    fused_kernel<<<BATCH / 32, 256, 0, stream>>>(
        user_ids, item_ids, rec_target, user_tbl, item_tbl, entity_tbl,
        w_vv, w_ev, w_ve, w_ee, bias_v, bias_e,
        Wut, bu, W1t, b1, W2t, b2, W3, b3, out);
}

// Round 3
// 155.880 us; speedup vs baseline: 1.5271x; 1.0783x over previous
//
#include <hip/hip_runtime.h>

#define BATCH 16384
#define DIM 128

typedef __attribute__((ext_vector_type(8))) short short8;
typedef __attribute__((ext_vector_type(4))) float floatx4;

__device__ __forceinline__ ushort f2bf(float f) {
    union { float f; uint u; } c; c.f = f;
    return (ushort)((c.u + 0x7FFFu + ((c.u >> 16) & 1u)) >> 16);
}
__device__ __forceinline__ float bf2f(ushort h) {
    union { uint u; float f; } c; c.u = ((uint)h) << 16;
    return c.f;
}
__device__ __forceinline__ ushort4 f4_to_bf4(float4 v) {
    return make_ushort4(f2bf(v.x), f2bf(v.y), f2bf(v.z), f2bf(v.w));
}

// Fragment-major slot index for a 32-row activation buffer with KT 32-col
// fragment groups: element (m,k) lives in 16B slot
//   ((m>>4)*KT + (k>>5))*64 + ((k>>3)&3)*16 + (m&15),  byte offset (k&7)*2.
// A wave's MFMA A-fragment (mt,kf) = slots [(mt*KT+kf)*64 + lane] -> lane-
// contiguous 16B reads: zero bank conflicts, fully dense.
__device__ __forceinline__ int slot_idx(int KT, int m, int k) {
    return (((m >> 4) * KT + (k >> 5)) << 6) + (((k >> 3) & 3) << 4) + (m & 15);
}

// ---------------------------------------------------------------------------
// Weight convert: fp32 [K][N] -> bf16 fragment-major [frag(nt,kf)][lane].
// One wave per 16x32 fragment; lane(q,r) holds W[k0+q*8+j][n0+r], j=0..7.
// Frag counts: Wu 8x4=32, W1 16x8=128, W2 8x8=64 -> 224 waves = 56 blocks.
// ---------------------------------------------------------------------------
__global__ __launch_bounds__(256) void convert_kernel(
    const float* __restrict__ Wu, const float* __restrict__ W1,
    const float* __restrict__ W2, short8* __restrict__ WF)
{
    const int f    = blockIdx.x * 4 + (threadIdx.x >> 6);
    const int lane = threadIdx.x & 63;
    const int q = lane >> 4, r = lane & 15;
    const float* W; int N, nt, kf, fl; short8* dst;
    if (f < 32)       { W = Wu; N = 128; fl = f;       nt = fl >> 2; kf = fl & 3; dst = WF;         }
    else if (f < 160) { W = W1; N = 256; fl = f - 32;  nt = fl >> 3; kf = fl & 7; dst = WF + 2048;  }
    else              { W = W2; N = 128; fl = f - 160; nt = fl >> 3; kf = fl & 7; dst = WF + 10240; }
    const int n = nt * 16 + r, k0 = kf * 32 + q * 8;
    short8 v;
    #pragma unroll
    for (int j = 0; j < 8; ++j)
        v[j] = (short)f2bf(W[(size_t)(k0 + j) * N + n]);
    dst[fl * 64 + lane] = v;
}

// ---------------------------------------------------------------------------
// One MFMA layer on fragment-major buffers.
// KF = K/32 (src frag cols), NT = N/16 (output col tiles), DKT = dstN/32.
// A-frags cached in registers across the nt loop (they don't depend on nt).
// ---------------------------------------------------------------------------
template<int KF, int NT, int DKT>
__device__ __forceinline__ void layer_mfma(
    const short8* __restrict__ src, const short8* __restrict__ WF,
    const float* __restrict__ bias, ushort* __restrict__ dst, int tid)
{
    const int wave = tid >> 6, lane = tid & 63;
    const int q = lane >> 4, r = lane & 15;
    short8 a[2][KF];
    #pragma unroll
    for (int mt = 0; mt < 2; ++mt)
        #pragma unroll
        for (int kf = 0; kf < KF; ++kf)
            a[mt][kf] = src[(mt * KF + kf) * 64 + lane];
    #pragma unroll
    for (int nt = wave; nt < NT; nt += 4) {
        const int col = nt * 16 + r;
        short8 b[KF];
        #pragma unroll
        for (int kf = 0; kf < KF; ++kf)
            b[kf] = WF[(nt * KF + kf) * 64 + lane];
        const float bs = bias[col];
        const int kc = col >> 5, qc = (col >> 3) & 3, e = col & 7;
        #pragma unroll
        for (int mt = 0; mt < 2; ++mt) {
            floatx4 acc = {0.f, 0.f, 0.f, 0.f};
            #pragma unroll
            for (int kf = 0; kf < KF; ++kf)
                acc = __builtin_amdgcn_mfma_f32_16x16x32_bf16(a[mt][kf], b[kf], acc, 0, 0, 0);
            #pragma unroll
            for (int rr = 0; rr < 4; ++rr) {
                const int rlow = q * 4 + rr;   // row & 15
                dst[(size_t)((((mt * DKT + kc) << 6) + (qc << 4) + rlow) * 8 + e)] =
                    f2bf(fmaxf(acc[rr] + bs, 0.f));
            }
        }
    }
}

// ---------------------------------------------------------------------------
// Fully fused model: 32 rows/block, 512 blocks, 256 threads.
// ---------------------------------------------------------------------------
__global__ __launch_bounds__(256) void fused_kernel(
    const int* __restrict__ user_ids, const int* __restrict__ item_ids,
    const float* __restrict__ rec_target,
    const float* __restrict__ user_tbl, const float* __restrict__ item_tbl,
    const float* __restrict__ entity_tbl,
    const float* __restrict__ w_vv, const float* __restrict__ w_ev,
    const float* __restrict__ w_ve, const float* __restrict__ w_ee,
    const float* __restrict__ bias_v, const float* __restrict__ bias_e,
    const short8* __restrict__ WF, const float* __restrict__ bu,
    const float* __restrict__ b1, const float* __restrict__ b2,
    const float* __restrict__ W3, const float* __restrict__ b3,
    float* __restrict__ out)
{
    __shared__ short8 sU0[512];    // user in   [32][128] frag-major (KT=4)
    __shared__ short8 sU1[512];    // user mid  (KT=4)
    __shared__ short8 sHI[1024];   // high      [32][256] (KT=8)
    __shared__ short8 sH1[1024];   // mlp1 out  (KT=8)
    __shared__ short8 sH2[512];    // mlp2 out  (KT=4)

    const int r0  = blockIdx.x * 32;
    const int tid = threadIdx.x;
    const int row = tid >> 3, l = tid & 7;   // 8 threads per row

    if (tid < 32) out[BATCH + r0 + tid] = rec_target[r0 + tid];

    // --- gather user rows -> bf16 -> sU0 (frag-major) ---
    {
        const int uid = user_ids[r0 + row];
        const float4* src = (const float4*)(user_tbl + (size_t)uid * DIM + l * 16);
        ushort* p = (ushort*)sU0;
        #pragma unroll
        for (int i = 0; i < 4; ++i) {
            const int col = l * 16 + i * 4;
            *(ushort4*)&p[slot_idx(4, row, col) * 8 + (col & 7)] = f4_to_bf4(src[i]);
        }
    }

    // --- cross-compress (2 layers, fp32) -> sHI cols 128..255 ---
    {
        const int id = item_ids[r0 + row];
        const float4* ip = (const float4*)(item_tbl   + (size_t)id * DIM + l * 16);
        const float4* hp = (const float4*)(entity_tbl + (size_t)id * DIM + l * 16);
        float4 it4[4], hd4[4];
        #pragma unroll
        for (int i = 0; i < 4; ++i) { it4[i] = ip[i]; hd4[i] = hp[i]; }
        const float bv = bias_v[0], be = bias_e[0];
        #pragma unroll
        for (int lay = 0; lay < 2; ++lay) {
            float hv = 0.f, iv = 0.f, he = 0.f, ie = 0.f;
            #pragma unroll
            for (int i = 0; i < 4; ++i) {
                float4 wvv = ((const float4*)w_vv)[l * 4 + i];
                float4 wev = ((const float4*)w_ev)[l * 4 + i];
                float4 wve = ((const float4*)w_ve)[l * 4 + i];
                float4 wee = ((const float4*)w_ee)[l * 4 + i];
                hv += hd4[i].x * wvv.x + hd4[i].y * wvv.y + hd4[i].z * wvv.z + hd4[i].w * wvv.w;
                iv += it4[i].x * wev.x + it4[i].y * wev.y + it4[i].z * wev.z + it4[i].w * wev.w;
                he += hd4[i].x * wve.x + hd4[i].y * wve.y + hd4[i].z * wve.z + hd4[i].w * wve.w;
                ie += it4[i].x * wee.x + it4[i].y * wee.y + it4[i].z * wee.z + it4[i].w * wee.w;
            }
            hv += __shfl_xor(hv, 1); hv += __shfl_xor(hv, 2); hv += __shfl_xor(hv, 4);
            iv += __shfl_xor(iv, 1); iv += __shfl_xor(iv, 2); iv += __shfl_xor(iv, 4);
            he += __shfl_xor(he, 1); he += __shfl_xor(he, 2); he += __shfl_xor(he, 4);
            ie += __shfl_xor(ie, 1); ie += __shfl_xor(ie, 2); ie += __shfl_xor(ie, 4);
            #pragma unroll
            for (int i = 0; i < 4; ++i) {
                float4 t = it4[i], h = hd4[i];
                it4[i].x = t.x * hv + h.x * iv + bv;  hd4[i].x = t.x * he + h.x * ie + be;
                it4[i].y = t.y * hv + h.y * iv + bv;  hd4[i].y = t.y * he + h.y * ie + be;
                it4[i].z = t.z * hv + h.z * iv + bv;  hd4[i].z = t.z * he + h.z * ie + be;
                it4[i].w = t.w * hv + h.w * iv + bv;  hd4[i].w = t.w * he + h.w * ie + be;
            }
        }
        ushort* p = (ushort*)sHI;
        #pragma unroll
        for (int i = 0; i < 4; ++i) {
            const int col = 128 + l * 16 + i * 4;
            *(ushort4*)&p[slot_idx(8, row, col) * 8 + (col & 7)] = f4_to_bf4(it4[i]);
        }
    }
    __syncthreads();

    layer_mfma<4, 8, 4>(sU0, WF,          bu, (ushort*)sU1, tid);   // user L1
    __syncthreads();
    layer_mfma<4, 8, 8>(sU1, WF,          bu, (ushort*)sHI, tid);   // user L2 -> high[:,0:128]
    __syncthreads();
    layer_mfma<8, 16, 8>(sHI, WF + 2048,  b1, (ushort*)sH1, tid);   // mlp1
    __syncthreads();
    layer_mfma<8, 8, 4>(sH1, WF + 10240,  b2, (ushort*)sH2, tid);   // mlp2
    __syncthreads();

    // --- mlp3: per-row dot with W3[128] + b3, relu ---
    {
        float p = 0.f;
        #pragma unroll
        for (int i = 0; i < 2; ++i) {
            const int c8 = l * 2 + i;
            short8 h = sH2[(((row >> 4) * 4 + (c8 >> 2)) << 6) + ((c8 & 3) << 4) + (row & 15)];
            float4 w0 = ((const float4*)W3)[c8 * 2];
            float4 w1 = ((const float4*)W3)[c8 * 2 + 1];
            p += bf2f((ushort)h[0]) * w0.x + bf2f((ushort)h[1]) * w0.y
               + bf2f((ushort)h[2]) * w0.z + bf2f((ushort)h[3]) * w0.w
               + bf2f((ushort)h[4]) * w1.x + bf2f((ushort)h[5]) * w1.y
               + bf2f((ushort)h[6]) * w1.z + bf2f((ushort)h[7]) * w1.w;
        }
        p += __shfl_xor(p, 1); p += __shfl_xor(p, 2); p += __shfl_xor(p, 4);
        if (l == 0) out[r0 + row] = fmaxf(p + b3[0], 0.f);
    }
}

// ---------------------------------------------------------------------------
extern "C" void kernel_launch(void* const* d_in, const int* in_sizes, int n_in,
                              void* d_out, int out_size, void* d_ws, size_t ws_size,
                              hipStream_t stream)
{
    const int*   user_ids   = (const int*)  d_in[0];
    const int*   item_ids   = (const int*)  d_in[1];
    const float* rec_target = (const float*)d_in[2];
    const float* user_tbl   = (const float*)d_in[3];
    const float* item_tbl   = (const float*)d_in[4];
    const float* entity_tbl = (const float*)d_in[5];
    const float* w_vv       = (const float*)d_in[6];
    const float* w_ev       = (const float*)d_in[7];
    const float* w_ve       = (const float*)d_in[8];
    const float* w_ee       = (const float*)d_in[9];
    const float* bias_v     = (const float*)d_in[10];
    const float* bias_e     = (const float*)d_in[11];
    const float* Wu         = (const float*)d_in[12];
    const float* bu         = (const float*)d_in[13];
    const float* W1         = (const float*)d_in[14];
    const float* b1         = (const float*)d_in[15];
    const float* W2         = (const float*)d_in[16];
    const float* b2         = (const float*)d_in[17];
    const float* W3         = (const float*)d_in[18];
    const float* b3         = (const float*)d_in[19];
    float* out = (float*)d_out;

    short8* WF = (short8*)d_ws;   // Wu frags [0,2048) | W1 [2048,10240) | W2 [10240,14336)

    convert_kernel<<<56, 256, 0, stream>>>(Wu, W1, W2, WF);
    fused_kernel<<<BATCH / 32, 256, 0, stream>>>(
        user_ids, item_ids, rec_target, user_tbl, item_tbl, entity_tbl,
        w_vv, w_ev, w_ve, w_ee, bias_v, bias_e,
        WF, bu, b1, b2, W3, b3, out);
}